// Round 1
// baseline (1147.711 us; speedup 1.0000x reference)
//
#include <hip/hip_runtime.h>

// Problem dims
#define BB 32
#define TT 2048
#define FF 400
#define HH 1152
#define MM 65536      // BB*TT
#define NN 3456       // 3*HH
#define KK 800        // 2*FF
#define MT 512        // MM/128
#define NT 27         // NN/128
#define KTL 25        // KK/32

typedef __attribute__((ext_vector_type(8))) short short8;
typedef __attribute__((ext_vector_type(4))) float f32x4;

__device__ __forceinline__ unsigned short f2bf(float f) {
  union { float f; unsigned u; } v; v.f = f;
  unsigned r = v.u + 0x7FFFu + ((v.u >> 16) & 1u);
  return (unsigned short)(r >> 16);
}

__device__ __forceinline__ void async16(void* lds, const void* g) {
  __builtin_amdgcn_global_load_lds((const __attribute__((address_space(1))) void*)g,
                                   (__attribute__((address_space(3))) void*)lds, 16, 0, 0);
}

// W [800][3456] fp32 -> bf16 tiled [nt][kt][kgrp][n][8]
__global__ __launch_bounds__(256) void pack_W_k(const float* __restrict__ W,
                                                unsigned short* __restrict__ Wws) {
  const int nt = blockIdx.x, kt = blockIdx.y;
  for (int c = threadIdx.x; c < 512; c += 256) {
    const int kg = c >> 7, n = c & 127;
    const int g = nt * 128 + n;
    const int k0 = kt * 32 + kg * 8;
    short8 o;
#pragma unroll
    for (int j = 0; j < 8; ++j) o[j] = (short)f2bf(W[(size_t)(k0 + j) * NN + g]);
    *(short8*)(Wws + ((size_t)(nt * KTL + kt) * 512 + c) * 8) = o;
  }
}

// merged = [x_t | x_{t-1}] -> bf16 tiled [mt][kt][kgrp][mm][8]
__global__ __launch_bounds__(256) void pack_A_k(const float* __restrict__ x,
                                                unsigned short* __restrict__ Aws) {
  const int mt = blockIdx.x, kt = blockIdx.y;
  for (int c = threadIdx.x; c < 512; c += 256) {
    const int kg = c >> 7, mm = c & 127;
    const int m = mt * 128 + mm;
    const int b = m >> 11, t = m & 2047;
    const int k = kt * 32 + kg * 8;
    short8 o;
    const float* src = nullptr;
    if (k < FF) src = x + (size_t)(b * TT + t) * FF + k;
    else if (t > 0) src = x + (size_t)(b * TT + t - 1) * FF + (k - FF);
    if (src) {
      f32x4 v0 = *(const f32x4*)(src);
      f32x4 v1 = *(const f32x4*)(src + 4);
#pragma unroll
      for (int j = 0; j < 4; ++j) o[j] = (short)f2bf(v0[j]);
#pragma unroll
      for (int j = 0; j < 4; ++j) o[4 + j] = (short)f2bf(v1[j]);
    } else {
#pragma unroll
      for (int j = 0; j < 8; ++j) o[j] = 0;
    }
    *(short8*)(Aws + ((size_t)(mt * KTL + kt) * 512 + c) * 8) = o;
  }
}

// C = A(bf16) * W(bf16), fused bias + activations.
// z(tanh) -> Z ws, f(sigmoid) -> Fv ws, o(sigmoid) -> Out (d_out)
__global__ __launch_bounds__(256) void gemm_k(const unsigned short* __restrict__ Aws,
                                              const unsigned short* __restrict__ Wws,
                                              const float* __restrict__ bias,
                                              float* __restrict__ Z,
                                              float* __restrict__ Fv,
                                              float* __restrict__ Out) {
  __shared__ unsigned short As[2][4096];
  __shared__ unsigned short Bs[2][4096];
  const int nt = blockIdx.x, mt = blockIdx.y;
  const int tid = threadIdx.x;
  const int lane = tid & 63, w = tid >> 6;
  const int wr = w >> 1, wc = w & 1;
  const int l15 = lane & 15, kg = lane >> 4;

  const unsigned short* ga = Aws + (size_t)mt * KTL * 4096 + tid * 8;
  const unsigned short* gb = Wws + (size_t)nt * KTL * 4096 + tid * 8;

  f32x4 acc[4][4] = {};

  // prologue: stage kt=0 into buffer 0
  async16(&As[0][tid * 8], ga);
  async16(&As[0][2048 + tid * 8], ga + 2048);
  async16(&Bs[0][tid * 8], gb);
  async16(&Bs[0][2048 + tid * 8], gb + 2048);

  for (int kt = 0; kt < KTL; ++kt) {
    const int cur = kt & 1;
    __syncthreads();  // drains vmcnt (staged buf `cur` ready) + lgkm (prev reads done)
    if (kt + 1 < KTL) {
      const unsigned short* a2 = ga + (size_t)(kt + 1) * 4096;
      const unsigned short* b2 = gb + (size_t)(kt + 1) * 4096;
      async16(&As[cur ^ 1][tid * 8], a2);
      async16(&As[cur ^ 1][2048 + tid * 8], a2 + 2048);
      async16(&Bs[cur ^ 1][tid * 8], b2);
      async16(&Bs[cur ^ 1][2048 + tid * 8], b2 + 2048);
    }
    short8 af[4], bfr[4];
#pragma unroll
    for (int mr = 0; mr < 4; ++mr)
      af[mr] = *(const short8*)&As[cur][(size_t)(kg * 128 + wr * 64 + mr * 16 + l15) * 8];
#pragma unroll
    for (int nr = 0; nr < 4; ++nr)
      bfr[nr] = *(const short8*)&Bs[cur][(size_t)(kg * 128 + wc * 64 + nr * 16 + l15) * 8];
#pragma unroll
    for (int mr = 0; mr < 4; ++mr)
#pragma unroll
      for (int nr = 0; nr < 4; ++nr)
        acc[mr][nr] = __builtin_amdgcn_mfma_f32_16x16x32_bf16(af[mr], bfr[nr], acc[mr][nr], 0, 0, 0);
  }

  // epilogue: bias + activation, scatter by gate sector (whole block is one sector)
  const int sector = nt / 9;  // 0=z, 1=f, 2=o   (1152 = 9*128)
  float* __restrict__ dst = (sector == 0) ? Z : ((sector == 1) ? Fv : Out);
  const int gbase = nt * 128 + wc * 64 + l15;
  const int colbase = gbase - sector * 1152;
#pragma unroll
  for (int nr = 0; nr < 4; ++nr) {
    const float bv = bias[gbase + nr * 16];
    const int col = colbase + nr * 16;
#pragma unroll
    for (int mr = 0; mr < 4; ++mr) {
      const int row0 = mt * 128 + wr * 64 + mr * 16 + (lane >> 4) * 4;
      f32x4 v = acc[mr][nr];
#pragma unroll
      for (int r = 0; r < 4; ++r) {
        float xv = v[r] + bv;
        float s;
        if (sector == 0) {
          float e = __expf(2.0f * xv);   // tanh(x) = 1 - 2/(e^{2x}+1)
          s = 1.0f - 2.0f / (e + 1.0f);
        } else {
          s = 1.0f / (1.0f + __expf(-xv));
        }
        dst[(size_t)(row0 + r) * HH + col] = s;
      }
    }
  }
}

// h_t = h_{t-1} + f*(z - h_{t-1});  c_t = o*h_t  (reads o from Out, overwrites with c)
__global__ __launch_bounds__(256) void scan_k(const float* __restrict__ Z,
                                              const float* __restrict__ Fv,
                                              const float* __restrict__ h0,
                                              float* __restrict__ Out) {
  const int idx = blockIdx.x * 256 + threadIdx.x;
  const int b = idx / HH;
  const int h = idx - b * HH;
  size_t p = (size_t)b * TT * HH + h;
  float hs = h0[idx];
#pragma unroll 8
  for (int t = 0; t < TT; ++t, p += HH) {
    float z = Z[p], f = Fv[p], o = Out[p];
    hs = fmaf(f, z - hs, hs);
    Out[p] = o * hs;
  }
}

extern "C" void kernel_launch(void* const* d_in, const int* in_sizes, int n_in,
                              void* d_out, int out_size, void* d_ws, size_t ws_size,
                              hipStream_t stream) {
  const float* x    = (const float*)d_in[0];
  const float* W    = (const float*)d_in[1];
  const float* bias = (const float*)d_in[2];
  const float* h0   = (const float*)d_in[3];
  float* Out = (float*)d_out;
  char* ws = (char*)d_ws;

  // ws layout
  const size_t A_BYTES = (size_t)MT * KTL * 8192;          // 104,857,600
  const size_t W_BYTES = (size_t)NT * KTL * 8192;          //   5,529,600
  const size_t G_BYTES = (size_t)MM * HH * 4;              // 301,989,888
  unsigned short* Aws = (unsigned short*)ws;
  unsigned short* Wws = (unsigned short*)(ws + A_BYTES);
  float* Z  = (float*)(ws + A_BYTES + W_BYTES);
  float* Fv = (float*)(ws + A_BYTES + W_BYTES + G_BYTES);
  (void)ws_size; (void)in_sizes; (void)n_in; (void)out_size;

  pack_W_k<<<dim3(NT, KTL), 256, 0, stream>>>(W, Wws);
  pack_A_k<<<dim3(MT, KTL), 256, 0, stream>>>(x, Aws);
  gemm_k<<<dim3(NT, MT), 256, 0, stream>>>(Aws, Wws, bias, Z, Fv, Out);
  scan_k<<<dim3(MM * HH / TT / 256 / 2048 * 2048 == 0 ? 144 : 144), 256, 0, stream>>>(Z, Fv, h0, Out);
}

// Round 2
// 998.529 us; speedup vs baseline: 1.1494x; 1.1494x over previous
//
#include <hip/hip_runtime.h>

// Problem dims
#define BB 32
#define TT 2048
#define FF 400
#define HH 1152
#define MM 65536      // BB*TT
#define NN 3456       // 3*HH
#define KK 800        // 2*FF
#define MT2 256       // MM/256  (BM=256)
#define NT 27         // NN/128  (BN=128)
#define KTL 25        // KK/32   (BK=32)

typedef __attribute__((ext_vector_type(8))) short short8;
typedef __attribute__((ext_vector_type(4))) float f32x4;

__device__ __forceinline__ unsigned short f2bf(float f) {
  union { float f; unsigned u; } v; v.f = f;
  unsigned r = v.u + 0x7FFFu + ((v.u >> 16) & 1u);
  return (unsigned short)(r >> 16);
}

__device__ __forceinline__ void async16(void* lds, const void* g) {
  __builtin_amdgcn_global_load_lds((const __attribute__((address_space(1))) void*)g,
                                   (__attribute__((address_space(3))) void*)lds, 16, 0, 0);
}

// W [800][3456] fp32 -> bf16 tiled [nt][kt][kg][n(128)][8]
__global__ __launch_bounds__(256) void pack_W_k(const float* __restrict__ W,
                                                unsigned short* __restrict__ Wws) {
  const int nt = blockIdx.x, kt = blockIdx.y;
  for (int c = threadIdx.x; c < 512; c += 256) {
    const int kg = c >> 7, n = c & 127;
    const int g = nt * 128 + n;
    const int k0 = kt * 32 + kg * 8;
    short8 o;
#pragma unroll
    for (int j = 0; j < 8; ++j) o[j] = (short)f2bf(W[(size_t)(k0 + j) * NN + g]);
    *(short8*)(Wws + ((size_t)(nt * KTL + kt) * 512 + c) * 8) = o;
  }
}

// merged = [x_t | x_{t-1}] -> bf16 tiled [mt][kt][kg][mm(256)][8]
__global__ __launch_bounds__(256) void pack_A_k(const float* __restrict__ x,
                                                unsigned short* __restrict__ Aws) {
  const int mt = blockIdx.x, kt = blockIdx.y;
  for (int c = threadIdx.x; c < 1024; c += 256) {
    const int kg = c >> 8, mm = c & 255;
    const int m = mt * 256 + mm;
    const int b = m >> 11, t = m & 2047;
    const int k = kt * 32 + kg * 8;
    short8 o;
    const float* src = nullptr;
    if (k < FF) src = x + (size_t)(b * TT + t) * FF + k;
    else if (t > 0) src = x + (size_t)(b * TT + t - 1) * FF + (k - FF);
    if (src) {
      f32x4 v0 = *(const f32x4*)(src);
      f32x4 v1 = *(const f32x4*)(src + 4);
#pragma unroll
      for (int j = 0; j < 4; ++j) o[j] = (short)f2bf(v0[j]);
#pragma unroll
      for (int j = 0; j < 4; ++j) o[4 + j] = (short)f2bf(v1[j]);
    } else {
#pragma unroll
      for (int j = 0; j < 8; ++j) o[j] = 0;
    }
    *(short8*)(Aws + ((size_t)(mt * KTL + kt) * 1024 + c) * 8) = o;
  }
}

// C = A(bf16) * W(bf16), 256x128 tile, 8 waves (4M x 2N), BK=32, dbuf LDS.
// Fused bias + activations; z(tanh)->Z, f(sig)->Fv, o(sig)->Out.
__global__ __launch_bounds__(512) void gemm_k(const unsigned short* __restrict__ Aws,
                                              const unsigned short* __restrict__ Wws,
                                              const float* __restrict__ bias,
                                              float* __restrict__ Z,
                                              float* __restrict__ Fv,
                                              float* __restrict__ Out) {
  __shared__ unsigned short As[2][8192];  // [kg(4)][mm(256)][8]
  __shared__ unsigned short Bs[2][4096];  // [kg(4)][n(128)][8]

  // XCD-bijective swizzle: 6912 blocks = 8 XCDs x 864; nt-fastest within XCD
  // so the 27 blocks sharing one A-tile run on ONE XCD's L2.
  const int bid = blockIdx.x;
  const int swz = (bid & 7) * 864 + (bid >> 3);
  const int mt = swz / 27;
  const int nt = swz - mt * 27;

  const int tid = threadIdx.x;
  const int lane = tid & 63, w = tid >> 6;
  const int wr = w >> 1, wc = w & 1;          // 4 M-waves x 2 N-waves
  const int l15 = lane & 15, kg = lane >> 4;

  const unsigned short* ga = Aws + (size_t)mt * KTL * 8192;
  const unsigned short* gb = Wws + (size_t)nt * KTL * 4096;

  f32x4 acc[4][4] = {};

  // prologue: stage kt=0 into buffer 0 (A: 2 issues, B: 1 issue; 512 thr x 16B)
  async16(&As[0][tid * 8], ga + tid * 8);
  async16(&As[0][4096 + tid * 8], ga + 4096 + tid * 8);
  async16(&Bs[0][tid * 8], gb + tid * 8);

  for (int kt = 0; kt < KTL; ++kt) {
    const int cur = kt & 1;
    __syncthreads();  // drains vmcnt (staged buf `cur` ready) + lgkm (prev reads done)
    if (kt + 1 < KTL) {
      const unsigned short* a2 = ga + (size_t)(kt + 1) * 8192;
      const unsigned short* b2 = gb + (size_t)(kt + 1) * 4096;
      async16(&As[cur ^ 1][tid * 8], a2 + tid * 8);
      async16(&As[cur ^ 1][4096 + tid * 8], a2 + 4096 + tid * 8);
      async16(&Bs[cur ^ 1][tid * 8], b2 + tid * 8);
    }
    short8 af[4], bfr[4];
#pragma unroll
    for (int mr = 0; mr < 4; ++mr)
      af[mr] = *(const short8*)&As[cur][(size_t)(kg * 256 + wr * 64 + mr * 16 + l15) * 8];
#pragma unroll
    for (int nr = 0; nr < 4; ++nr)
      bfr[nr] = *(const short8*)&Bs[cur][(size_t)(kg * 128 + wc * 64 + nr * 16 + l15) * 8];
#pragma unroll
    for (int mr = 0; mr < 4; ++mr)
#pragma unroll
      for (int nr = 0; nr < 4; ++nr)
        acc[mr][nr] = __builtin_amdgcn_mfma_f32_16x16x32_bf16(af[mr], bfr[nr], acc[mr][nr], 0, 0, 0);
  }

  // epilogue: bias + activation, scatter by gate sector (block is one sector: 1152=9*128)
  const int sector = nt / 9;  // 0=z, 1=f, 2=o
  float* __restrict__ dst = (sector == 0) ? Z : ((sector == 1) ? Fv : Out);
  const int gbase = nt * 128 + wc * 64 + l15;
  const int colbase = gbase - sector * 1152;
#pragma unroll
  for (int nr = 0; nr < 4; ++nr) {
    const float bv = bias[gbase + nr * 16];
    const int col = colbase + nr * 16;
#pragma unroll
    for (int mr = 0; mr < 4; ++mr) {
      const int row0 = mt * 256 + wr * 64 + mr * 16 + (lane >> 4) * 4;
      f32x4 v = acc[mr][nr];
#pragma unroll
      for (int r = 0; r < 4; ++r) {
        float xv = v[r] + bv;
        float s;
        if (sector == 0) {
          float e = __expf(2.0f * xv);   // tanh(x) = 1 - 2/(e^{2x}+1)
          s = 1.0f - 2.0f / (e + 1.0f);
        } else {
          s = 1.0f / (1.0f + __expf(-xv));
        }
        dst[(size_t)(row0 + r) * HH + col] = s;
      }
    }
  }
}

// h_t = h_{t-1} + f*(z - h_{t-1});  c_t = o*h_t  (reads o from Out, overwrites with c)
// 64-thread blocks: 576 blocks -> covers all 256 CUs (was 144 blocks @256thr).
__global__ __launch_bounds__(64) void scan_k(const float* __restrict__ Z,
                                             const float* __restrict__ Fv,
                                             const float* __restrict__ h0,
                                             float* __restrict__ Out) {
  const int idx = blockIdx.x * 64 + threadIdx.x;
  const int b = idx / HH;
  const int h = idx - b * HH;
  size_t p = (size_t)b * TT * HH + h;
  float hs = h0[idx];
#pragma unroll 8
  for (int t = 0; t < TT; ++t, p += HH) {
    float z = Z[p], f = Fv[p], o = Out[p];
    hs = fmaf(f, z - hs, hs);
    Out[p] = o * hs;
  }
}

extern "C" void kernel_launch(void* const* d_in, const int* in_sizes, int n_in,
                              void* d_out, int out_size, void* d_ws, size_t ws_size,
                              hipStream_t stream) {
  const float* x    = (const float*)d_in[0];
  const float* W    = (const float*)d_in[1];
  const float* bias = (const float*)d_in[2];
  const float* h0   = (const float*)d_in[3];
  float* Out = (float*)d_out;
  char* ws = (char*)d_ws;

  // ws layout
  const size_t A_BYTES = (size_t)MT2 * KTL * 16384;        // 104,857,600
  const size_t W_BYTES = (size_t)NT * KTL * 8192;          //   5,529,600
  const size_t G_BYTES = (size_t)MM * HH * 4;              // 301,989,888
  unsigned short* Aws = (unsigned short*)ws;
  unsigned short* Wws = (unsigned short*)(ws + A_BYTES);
  float* Z  = (float*)(ws + A_BYTES + W_BYTES);
  float* Fv = (float*)(ws + A_BYTES + W_BYTES + G_BYTES);
  (void)ws_size; (void)in_sizes; (void)n_in; (void)out_size;

  pack_W_k<<<dim3(NT, KTL), 256, 0, stream>>>(W, Wws);
  pack_A_k<<<dim3(MT2, KTL), 256, 0, stream>>>(x, Aws);
  gemm_k<<<MT2 * NT, 512, 0, stream>>>(Aws, Wws, bias, Z, Fv, Out);
  scan_k<<<MM * HH / TT / 64, 64, 0, stream>>>(Z, Fv, h0, Out);
}

// Round 3
// 880.658 us; speedup vs baseline: 1.3032x; 1.1338x over previous
//
#include <hip/hip_runtime.h>

// Problem dims
#define BB 32
#define TT 2048
#define FF 400
#define HH 1152
#define MM 65536      // BB*TT
#define NN 3456       // 3*HH
#define KK 800        // 2*FF
#define MT2 256       // MM/256  (BM=256)
#define NT 27         // NN/128  (BN=128)
#define KT13 13       // ceil(KK/64) -> K padded to 832 with zeros

typedef __attribute__((ext_vector_type(8))) short short8;
typedef __attribute__((ext_vector_type(4))) float f32x4;
typedef _Float16 h2 __attribute__((ext_vector_type(2)));
typedef float f2 __attribute__((ext_vector_type(2)));

__device__ __forceinline__ unsigned short f2bf(float f) {
  union { float f; unsigned u; } v; v.f = f;
  unsigned r = v.u + 0x7FFFu + ((v.u >> 16) & 1u);
  return (unsigned short)(r >> 16);
}

__device__ __forceinline__ void async16(void* lds, const void* g) {
  __builtin_amdgcn_global_load_lds((const __attribute__((address_space(1))) void*)g,
                                   (__attribute__((address_space(3))) void*)lds, 16, 0, 0);
}

// W [800][3456] fp32 -> bf16 tiled [nt][kt][ks(2)][kg(4)][n(128)][8], zero-padded k>=800
__global__ __launch_bounds__(256) void pack_W_k(const float* __restrict__ W,
                                                unsigned short* __restrict__ Wws) {
  const int nt = blockIdx.x, kt = blockIdx.y;
  for (int c = threadIdx.x; c < 1024; c += 256) {   // 1024 short8 per tile
    const int ks = c >> 9, kg = (c >> 7) & 3, n = c & 127;
    const int g = nt * 128 + n;
    const int k0 = kt * 64 + ks * 32 + kg * 8;
    short8 o;
    if (k0 < KK) {
#pragma unroll
      for (int j = 0; j < 8; ++j) o[j] = (short)f2bf(W[(size_t)(k0 + j) * NN + g]);
    } else {
#pragma unroll
      for (int j = 0; j < 8; ++j) o[j] = 0;
    }
    *(short8*)(Wws + ((size_t)(nt * KT13 + kt) * 1024 + c) * 8) = o;
  }
}

// merged = [x_t | x_{t-1}] -> bf16 tiled [mt][kt][ks(2)][kg(4)][mm(256)][8], zero-padded
__global__ __launch_bounds__(256) void pack_A_k(const float* __restrict__ x,
                                                unsigned short* __restrict__ Aws) {
  const int mt = blockIdx.x, kt = blockIdx.y;
  for (int c = threadIdx.x; c < 2048; c += 256) {   // 2048 short8 per tile
    const int ks = c >> 10, kg = (c >> 8) & 3, mm = c & 255;
    const int m = mt * 256 + mm;
    const int b = m >> 11, t = m & 2047;
    const int k = kt * 64 + ks * 32 + kg * 8;
    short8 o;
    const float* src = nullptr;
    if (k < FF) src = x + (size_t)(b * TT + t) * FF + k;
    else if (k < KK && t > 0) src = x + (size_t)(b * TT + t - 1) * FF + (k - FF);
    if (src) {
      f32x4 v0 = *(const f32x4*)(src);
      f32x4 v1 = *(const f32x4*)(src + 4);
#pragma unroll
      for (int j = 0; j < 4; ++j) o[j] = (short)f2bf(v0[j]);
#pragma unroll
      for (int j = 0; j < 4; ++j) o[4 + j] = (short)f2bf(v1[j]);
    } else {
#pragma unroll
      for (int j = 0; j < 8; ++j) o[j] = 0;
    }
    *(short8*)(Aws + ((size_t)(mt * KT13 + kt) * 2048 + c) * 8) = o;
  }
}

// C = A(bf16) * W(bf16), 256x128 tile, 8 waves (4M x 2N), BK=64,
// triple-buffered LDS, 2-deep prefetch, counted vmcnt (T3+T4), setprio (T5).
// Fused bias + activations; z(tanh)/f(sig)/o(sig) -> fp16 ws buffers.
__global__ __launch_bounds__(512) void gemm_k(const unsigned short* __restrict__ Aws,
                                              const unsigned short* __restrict__ Wws,
                                              const float* __restrict__ bias,
                                              _Float16* __restrict__ Zh,
                                              _Float16* __restrict__ Fh,
                                              _Float16* __restrict__ Oh) {
  __shared__ unsigned short As[3][16384];  // [ks(2)][kg(4)][mm(256)][8] per buffer
  __shared__ unsigned short Bs[3][8192];   // [ks(2)][kg(4)][n(128)][8]

  // XCD-bijective swizzle: 6912 = 8 XCDs x 864; nt-fastest within an XCD.
  const int bid = blockIdx.x;
  const int swz = (bid & 7) * 864 + (bid >> 3);
  const int mt = swz / 27;
  const int nt = swz - mt * 27;

  const int tid = threadIdx.x;
  const int lane = tid & 63, w = tid >> 6;
  const int wr = w >> 1, wc = w & 1;          // 4 M-waves x 2 N-waves
  const int l15 = lane & 15, kg = lane >> 4;

  const unsigned short* ga = Aws + (size_t)mt * KT13 * 16384;
  const unsigned short* gb = Wws + (size_t)nt * KT13 * 8192;

  f32x4 acc[4][4] = {};

  // prologue: stage tiles 0 and 1 (6 issues each; order defines vmcnt counting)
#pragma unroll
  for (int t = 0; t < 2; ++t) {
    const unsigned short* a = ga + t * 16384;
    const unsigned short* b = gb + t * 8192;
    async16(&As[t][tid * 8], a + tid * 8);
    async16(&As[t][4096 + tid * 8], a + 4096 + tid * 8);
    async16(&As[t][8192 + tid * 8], a + 8192 + tid * 8);
    async16(&As[t][12288 + tid * 8], a + 12288 + tid * 8);
    async16(&Bs[t][tid * 8], b + tid * 8);
    async16(&Bs[t][4096 + tid * 8], b + 4096 + tid * 8);
  }

#pragma unroll
  for (int t = 0; t < KT13; ++t) {
    const int buf = t % 3;
    // wait for tile t's 6 loads (oldest); keep tile t+1's 6 in flight
    if (t < KT13 - 1) asm volatile("s_waitcnt vmcnt(6)" ::: "memory");
    else              asm volatile("s_waitcnt vmcnt(0)" ::: "memory");
    __builtin_amdgcn_s_barrier();

    // stage tile t+2 into buf (t+2)%3 == (t-1)%3 (reads of t-1 fenced by barrier above)
    if (t + 2 < KT13) {
      const int nbuf = (t + 2) % 3;
      const unsigned short* a = ga + (size_t)(t + 2) * 16384;
      const unsigned short* b = gb + (size_t)(t + 2) * 8192;
      async16(&As[nbuf][tid * 8], a + tid * 8);
      async16(&As[nbuf][4096 + tid * 8], a + 4096 + tid * 8);
      async16(&As[nbuf][8192 + tid * 8], a + 8192 + tid * 8);
      async16(&As[nbuf][12288 + tid * 8], a + 12288 + tid * 8);
      async16(&Bs[nbuf][tid * 8], b + tid * 8);
      async16(&Bs[nbuf][4096 + tid * 8], b + 4096 + tid * 8);
    }

    short8 af[2][4], bfv[2][4];
#pragma unroll
    for (int ks = 0; ks < 2; ++ks) {
#pragma unroll
      for (int mr = 0; mr < 4; ++mr)
        af[ks][mr] = *(const short8*)&As[buf][(size_t)(((ks * 4 + kg) * 256) + wr * 64 + mr * 16 + l15) * 8];
#pragma unroll
      for (int nr = 0; nr < 4; ++nr)
        bfv[ks][nr] = *(const short8*)&Bs[buf][(size_t)(((ks * 4 + kg) * 128) + wc * 64 + nr * 16 + l15) * 8];
    }

    __builtin_amdgcn_s_setprio(1);
#pragma unroll
    for (int ks = 0; ks < 2; ++ks)
#pragma unroll
      for (int mr = 0; mr < 4; ++mr)
#pragma unroll
        for (int nr = 0; nr < 4; ++nr)
          acc[mr][nr] = __builtin_amdgcn_mfma_f32_16x16x32_bf16(af[ks][mr], bfv[ks][nr], acc[mr][nr], 0, 0, 0);
    __builtin_amdgcn_s_setprio(0);
  }

  // epilogue: bias + activation -> fp16 gate buffers (block is one gate sector: 1152=9*128)
  const int sector = nt / 9;  // 0=z, 1=f, 2=o
  _Float16* __restrict__ dst = (sector == 0) ? Zh : ((sector == 1) ? Fh : Oh);
  const int gbase = nt * 128 + wc * 64 + l15;
  const int colbase = gbase - sector * 1152;
#pragma unroll
  for (int nr = 0; nr < 4; ++nr) {
    const float bv = bias[gbase + nr * 16];
    const int col = colbase + nr * 16;
#pragma unroll
    for (int mr = 0; mr < 4; ++mr) {
      const int row0 = mt * 256 + wr * 64 + mr * 16 + kg * 4;
      f32x4 v = acc[mr][nr];
#pragma unroll
      for (int r = 0; r < 4; ++r) {
        float xv = v[r] + bv;
        float s;
        if (sector == 0) {
          float e = __expf(2.0f * xv);   // tanh(x) = 1 - 2/(e^{2x}+1)
          s = 1.0f - 2.0f / (e + 1.0f);
        } else {
          s = 1.0f / (1.0f + __expf(-xv));
        }
        dst[(size_t)(row0 + r) * HH + col] = (_Float16)s;
      }
    }
  }
}

// h_t = h_{t-1} + f*(z - h_{t-1});  c_t = o*h_t.  2 h-lanes per thread (half2 loads).
__global__ __launch_bounds__(64) void scan_k(const h2* __restrict__ Zh,
                                             const h2* __restrict__ Fh,
                                             const h2* __restrict__ Oh,
                                             const float* __restrict__ h0,
                                             float* __restrict__ Out) {
  const int idx = blockIdx.x * 64 + threadIdx.x;   // pair index
  const int b = idx / (HH / 2);
  const int hp = idx - b * (HH / 2);
  size_t p = (size_t)b * TT * (HH / 2) + hp;
  float hs0 = h0[b * HH + hp * 2];
  float hs1 = h0[b * HH + hp * 2 + 1];
#pragma unroll 8
  for (int t = 0; t < TT; ++t, p += HH / 2) {
    h2 z = Zh[p], f = Fh[p], o = Oh[p];
    hs0 = fmaf((float)f[0], (float)z[0] - hs0, hs0);
    hs1 = fmaf((float)f[1], (float)z[1] - hs1, hs1);
    f2 c;
    c[0] = (float)o[0] * hs0;
    c[1] = (float)o[1] * hs1;
    *(f2*)&Out[p * 2] = c;
  }
}

extern "C" void kernel_launch(void* const* d_in, const int* in_sizes, int n_in,
                              void* d_out, int out_size, void* d_ws, size_t ws_size,
                              hipStream_t stream) {
  const float* x    = (const float*)d_in[0];
  const float* W    = (const float*)d_in[1];
  const float* bias = (const float*)d_in[2];
  const float* h0   = (const float*)d_in[3];
  float* Out = (float*)d_out;
  char* ws = (char*)d_ws;

  // ws layout
  const size_t A_BYTES = (size_t)MT2 * KT13 * 32768;       // 109,051,904
  const size_t W_BYTES = (size_t)NT * KT13 * 16384;        //   5,750,784
  const size_t G_BYTES = (size_t)MM * HH * 2;              // 150,994,944 (fp16 per gate)
  unsigned short* Aws = (unsigned short*)ws;
  unsigned short* Wws = (unsigned short*)(ws + A_BYTES);
  _Float16* Zh = (_Float16*)(ws + A_BYTES + W_BYTES);
  _Float16* Fh = (_Float16*)(ws + A_BYTES + W_BYTES + G_BYTES);
  _Float16* Oh = (_Float16*)(ws + A_BYTES + W_BYTES + 2 * G_BYTES);
  (void)ws_size; (void)in_sizes; (void)n_in; (void)out_size;

  pack_W_k<<<dim3(NT, KT13), 256, 0, stream>>>(W, Wws);
  pack_A_k<<<dim3(MT2, KT13), 256, 0, stream>>>(x, Aws);
  gemm_k<<<MT2 * NT, 512, 0, stream>>>(Aws, Wws, bias, Zh, Fh, Oh);
  scan_k<<<BB * HH / 2 / 64, 64, 0, stream>>>((const h2*)Zh, (const h2*)Fh, (const h2*)Oh, h0, Out);
}